// Round 1
// baseline (153.920 us; speedup 1.0000x reference)
//
#include <hip/hip_runtime.h>
#include <stdint.h>

#define BB 8
#define SS 8192
#define DD 512

#define TOK_CS 256
#define TOK_CE 257
#define TOK_MEM 258
#define TOK_TS 259
#define TOK_TE 260

#define SEGS 256           // segments per row
#define PB 32              // positions per segment (SS / SEGS)

typedef float vfloat4 __attribute__((ext_vector_type(4)));
typedef unsigned long long u64;

// ---------------------------------------------------------------------------
// Kernel 1 (meta): grid = B*SEGS = 2048 blocks x 256 threads.
// Identical scan logic to the previously-verified fused kernel, but instead of
// writing the 128 MB output it emits one 64-bit meta word per position to the
// workspace (512 KB total).
// meta bits: 0..47 one-hot mask | 48 TS | 49 TE | 50 MEM_EXEC | 52.. token
// ---------------------------------------------------------------------------
__global__ __launch_bounds__(256) void meta_kernel(const int* __restrict__ tokens,
                                                   u64* __restrict__ meta) {
    __shared__ int tloc[PB + 8];              // local tokens with 8-token front halo
    __shared__ int rcs[4];
    __shared__ int rce[4];

    const int blk = blockIdx.x;
    const int row = blk >> 8;                 // / SEGS
    const int seg = blk & (SEGS - 1);
    const int start = seg * PB;
    const int tid = threadIdx.x;
    const int lane = tid & 63;
    const int wv = tid >> 6;
    const int* rt = tokens + (size_t)row * SS;

    // ---- phase A: prefix carry over [0, start) ----
    int maxcs = -1, anyce = 0;
    for (int j = tid; j < start; j += 256) {   // strided; later j larger -> last hit = max
        int v = rt[j];
        if (v == TOK_CS) maxcs = j;
        if (v == TOK_CE) anyce = 1;
    }
    #pragma unroll
    for (int off = 32; off > 0; off >>= 1) {
        int a = __shfl_down(maxcs, off);
        int b = __shfl_down(anyce, off);
        if (a > maxcs) maxcs = a;
        anyce |= b;
    }
    if (lane == 0) { rcs[wv] = maxcs; rce[wv] = anyce; }

    // local tokens + halo
    if (tid < PB + 8) {
        int g = start - 8 + tid;
        tloc[tid] = (g >= 0) ? rt[g] : 0;     // 0 is never MEM
    }
    __syncthreads();
    int carry_cs = rcs[0], carry_ce = rce[0];
    #pragma unroll
    for (int w = 1; w < 4; ++w) {
        if (rcs[w] > carry_cs) carry_cs = rcs[w];
        carry_ce |= rce[w];
    }

    // ---- phase B: 32-lane inclusive (max,or) scan over PB positions ----
    if (tid < PB) {
        const int myv = tloc[8 + tid];
        int cs_scan = (myv == TOK_CS) ? (start + tid) : -1;
        int ce_scan = (myv == TOK_CE) ? 1 : 0;

        #pragma unroll
        for (int off = 1; off < PB; off <<= 1) {
            int u = __shfl_up(cs_scan, off);
            int w = __shfl_up(ce_scan, off);
            if (tid >= off) {
                if (u > cs_scan) cs_scan = u;
                ce_scan |= w;
            }
        }
        if (carry_cs > cs_scan) cs_scan = carry_cs;
        ce_scan |= carry_ce;

        const int i = start + tid;
        const int v = myv;
        u64 m = ((u64)v) << 52;

        // code-region address one-hot
        if (cs_scan >= 0 && ce_scan == 0 && v < 256) {
            int sp = i - cs_scan - 1;
            if (sp >= 0) {
                int bo = sp & 7;
                if (bo < 5) {
                    int addr = ((sp >> 3) << 3) + 2 + bo;   // PC_OFFSET=2
                    addr &= 4095;
                    m |= (1ull << (addr & 15))
                       | (1ull << (16 + ((addr >> 4) & 15)))
                       | (1ull << (32 + ((addr >> 8) & 15)));
                }
            }
        }

        // MEM-op scatter, gathered from up to 8 positions back
        #pragma unroll
        for (int off = 0; off < 4; ++off) {
            int jj = i - 5 - off;
            int lj = jj - start + 8;            // >= 0 since jj >= i-8 >= start-8
            if (jj >= 0 && (jj + 8) < SS && tloc[lj] == TOK_MEM) {
                int a = ((tloc[lj + 1] | (tloc[lj + 2] << 8)) & 4095) + off;
                a &= 4095;
                m |= (1ull << (a & 15))
                   | (1ull << (16 + ((a >> 4) & 15)))
                   | (1ull << (32 + ((a >> 8) & 15)));
            }
        }

        // flag dims
        if (v == TOK_TS) m |= (1ull << 48);
        if (v == TOK_TE) m |= (1ull << 49);
        if (v == TOK_MEM && (i + 8) < SS) m |= (1ull << 50);

        meta[(size_t)row * SS + start + tid] = m;
    }
}

// ---------------------------------------------------------------------------
// Kernel 2 (writer): pure stream. Grid = 2048 blocks x 256 threads
// (8 blocks/CU, no LDS, no barriers, minimal VGPR -> max occupancy).
// Each block streams 32 consecutive positions: meta -> embed gather -> patch
// -> nontemporal store. 128 f4 lanes x 2 positions per iteration.
// ---------------------------------------------------------------------------
__global__ __launch_bounds__(256) void write_kernel(const u64* __restrict__ meta,
                                                    const vfloat4* __restrict__ embed4,
                                                    vfloat4* __restrict__ out) {
    const int blk = blockIdx.x;
    const int tid = threadIdx.x;
    const int k = tid & 127;
    const int half = tid >> 7;                  // 0 or 1

    const size_t base = (size_t)blk * PB;       // global position of this block
    const u64* mrow = meta + base;
    vfloat4* orow = out + base * 128;

    #pragma unroll 8
    for (int it = 0; it < PB / 2; ++it) {
        const int pl = it * 2 + half;
        const u64 m = mrow[pl];                 // 8B broadcast within wave
        const int tok = (int)(m >> 52);

        vfloat4 v = embed4[tok * 128 + k];

        if (k >= 51 && k <= 63) {
            const int d0 = k * 4;
            #pragma unroll
            for (int j = 0; j < 4; ++j) {
                int r = d0 + j - 206;
                if (r >= 0 && r < 48 && ((m >> r) & 1ull)) v[j] = 1.0f;
            }
        } else if (k == 114) {
            #pragma unroll
            for (int j = 0; j < 3; ++j) {
                if ((m >> (48 + j)) & 1ull) v[j] = 1.0f;
            }
        }

        __builtin_nontemporal_store(v, &orow[pl * 128 + k]);
    }
}

extern "C" void kernel_launch(void* const* d_in, const int* in_sizes, int n_in,
                              void* d_out, int out_size, void* d_ws, size_t ws_size,
                              hipStream_t stream) {
    const float* embed = (const float*)d_in[0];   // [272, 512] fp32
    const int* tokens = (const int*)d_in[1];      // [8, 8192] int32

    u64* meta = (u64*)d_ws;                       // 8*8192*8B = 512 KB

    meta_kernel<<<BB * SEGS, 256, 0, stream>>>(tokens, meta);
    write_kernel<<<BB * SEGS, 256, 0, stream>>>(
        meta, (const vfloat4*)embed, (vfloat4*)d_out);
}

// Round 2
// 147.393 us; speedup vs baseline: 1.0443x; 1.0443x over previous
//
#include <hip/hip_runtime.h>
#include <stdint.h>

#define BB 8
#define SS 8192
#define DD 512

#define TOK_CS 256
#define TOK_CE 257
#define TOK_MEM 258
#define TOK_TS 259
#define TOK_TE 260

#define SEGS 256           // segments per row
#define PB 32              // positions per segment (SS / SEGS)

typedef float vfloat4 __attribute__((ext_vector_type(4)));
typedef unsigned long long u64;

// ---------------------------------------------------------------------------
// Kernel 1 (meta): grid = B*SEGS = 2048 blocks x 256 threads.
// Emits one 64-bit meta word per position to workspace (512 KB total).
// meta bits: 0..47 one-hot mask | 48 TS | 49 TE | 50 MEM_EXEC | 52.. token
// ---------------------------------------------------------------------------
__global__ __launch_bounds__(256) void meta_kernel(const int* __restrict__ tokens,
                                                   u64* __restrict__ meta) {
    __shared__ int tloc[PB + 8];              // local tokens with 8-token front halo
    __shared__ int rcs[4];
    __shared__ int rce[4];

    const int blk = blockIdx.x;
    const int row = blk >> 8;                 // / SEGS
    const int seg = blk & (SEGS - 1);
    const int start = seg * PB;
    const int tid = threadIdx.x;
    const int lane = tid & 63;
    const int wv = tid >> 6;
    const int* rt = tokens + (size_t)row * SS;

    // ---- phase A: prefix carry over [0, start) ----
    int maxcs = -1, anyce = 0;
    for (int j = tid; j < start; j += 256) {   // strided; later j larger -> last hit = max
        int v = rt[j];
        if (v == TOK_CS) maxcs = j;
        if (v == TOK_CE) anyce = 1;
    }
    #pragma unroll
    for (int off = 32; off > 0; off >>= 1) {
        int a = __shfl_down(maxcs, off);
        int b = __shfl_down(anyce, off);
        if (a > maxcs) maxcs = a;
        anyce |= b;
    }
    if (lane == 0) { rcs[wv] = maxcs; rce[wv] = anyce; }

    // local tokens + halo
    if (tid < PB + 8) {
        int g = start - 8 + tid;
        tloc[tid] = (g >= 0) ? rt[g] : 0;     // 0 is never MEM
    }
    __syncthreads();
    int carry_cs = rcs[0], carry_ce = rce[0];
    #pragma unroll
    for (int w = 1; w < 4; ++w) {
        if (rcs[w] > carry_cs) carry_cs = rcs[w];
        carry_ce |= rce[w];
    }

    // ---- phase B: 32-lane inclusive (max,or) scan over PB positions ----
    if (tid < PB) {
        const int myv = tloc[8 + tid];
        int cs_scan = (myv == TOK_CS) ? (start + tid) : -1;
        int ce_scan = (myv == TOK_CE) ? 1 : 0;

        #pragma unroll
        for (int off = 1; off < PB; off <<= 1) {
            int u = __shfl_up(cs_scan, off);
            int w = __shfl_up(ce_scan, off);
            if (tid >= off) {
                if (u > cs_scan) cs_scan = u;
                ce_scan |= w;
            }
        }
        if (carry_cs > cs_scan) cs_scan = carry_cs;
        ce_scan |= carry_ce;

        const int i = start + tid;
        const int v = myv;
        u64 m = ((u64)v) << 52;

        // code-region address one-hot
        if (cs_scan >= 0 && ce_scan == 0 && v < 256) {
            int sp = i - cs_scan - 1;
            if (sp >= 0) {
                int bo = sp & 7;
                if (bo < 5) {
                    int addr = ((sp >> 3) << 3) + 2 + bo;   // PC_OFFSET=2
                    addr &= 4095;
                    m |= (1ull << (addr & 15))
                       | (1ull << (16 + ((addr >> 4) & 15)))
                       | (1ull << (32 + ((addr >> 8) & 15)));
                }
            }
        }

        // MEM-op scatter, gathered from up to 8 positions back
        #pragma unroll
        for (int off = 0; off < 4; ++off) {
            int jj = i - 5 - off;
            int lj = jj - start + 8;            // >= 0 since jj >= i-8 >= start-8
            if (jj >= 0 && (jj + 8) < SS && tloc[lj] == TOK_MEM) {
                int a = ((tloc[lj + 1] | (tloc[lj + 2] << 8)) & 4095) + off;
                a &= 4095;
                m |= (1ull << (a & 15))
                   | (1ull << (16 + ((a >> 4) & 15)))
                   | (1ull << (32 + ((a >> 8) & 15)));
            }
        }

        // flag dims
        if (v == TOK_TS) m |= (1ull << 48);
        if (v == TOK_TE) m |= (1ull << 49);
        if (v == TOK_MEM && (i + 8) < SS) m |= (1ull << 50);

        meta[(size_t)row * SS + start + tid] = m;
    }
}

// ---------------------------------------------------------------------------
// Kernel 2 (writer): pure stream. Grid = 2048 blocks x 256 threads.
// SINGLE CHANGE vs R1: plain stores instead of __builtin_nontemporal_store
// (A/B the store flavor against the 6.26 TB/s fillBuffer reference).
// ---------------------------------------------------------------------------
__global__ __launch_bounds__(256) void write_kernel(const u64* __restrict__ meta,
                                                    const vfloat4* __restrict__ embed4,
                                                    vfloat4* __restrict__ out) {
    const int blk = blockIdx.x;
    const int tid = threadIdx.x;
    const int k = tid & 127;
    const int half = tid >> 7;                  // 0 or 1

    const size_t base = (size_t)blk * PB;       // global position of this block
    const u64* mrow = meta + base;
    vfloat4* orow = out + base * 128;

    #pragma unroll 8
    for (int it = 0; it < PB / 2; ++it) {
        const int pl = it * 2 + half;
        const u64 m = mrow[pl];                 // 8B broadcast within wave
        const int tok = (int)(m >> 52);

        vfloat4 v = embed4[tok * 128 + k];

        if (k >= 51 && k <= 63) {
            const int d0 = k * 4;
            #pragma unroll
            for (int j = 0; j < 4; ++j) {
                int r = d0 + j - 206;
                if (r >= 0 && r < 48 && ((m >> r) & 1ull)) v[j] = 1.0f;
            }
        } else if (k == 114) {
            #pragma unroll
            for (int j = 0; j < 3; ++j) {
                if ((m >> (48 + j)) & 1ull) v[j] = 1.0f;
            }
        }

        orow[pl * 128 + k] = v;                 // plain store (was nontemporal)
    }
}

extern "C" void kernel_launch(void* const* d_in, const int* in_sizes, int n_in,
                              void* d_out, int out_size, void* d_ws, size_t ws_size,
                              hipStream_t stream) {
    const float* embed = (const float*)d_in[0];   // [272, 512] fp32
    const int* tokens = (const int*)d_in[1];      // [8, 8192] int32

    u64* meta = (u64*)d_ws;                       // 8*8192*8B = 512 KB

    meta_kernel<<<BB * SEGS, 256, 0, stream>>>(tokens, meta);
    write_kernel<<<BB * SEGS, 256, 0, stream>>>(
        meta, (const vfloat4*)embed, (vfloat4*)d_out);
}